// Round 5
// baseline (121.003 us; speedup 1.0000x reference)
//
#include <hip/hip_runtime.h>
#include <hip/hip_bf16.h>

#define TT 24
#define NN 1000
#define DD 64
#define TCH 8                  // timesteps per wave (3 chunks)
#define NCH (TT / TCH)         // 3
#define NT  63                 // ceil(1000/16) node tiles of 16 rows

typedef short bf16x8 __attribute__((ext_vector_type(8)));
typedef float f32x4  __attribute__((ext_vector_type(4)));

__device__ __forceinline__ short f2bf(float f) {
    __hip_bfloat16 h = __float2bfloat16(f);
    return *reinterpret_cast<short*>(&h);
}
__device__ __forceinline__ float bf2f(short s) {
    union { unsigned u; float f; } c;
    c.u = ((unsigned)(unsigned short)s) << 16;
    return c.f;
}

// Barrier-free: no LDS, no __syncthreads. One wave = 16 nodes x 64 cols x TCH
// timesteps. A-fragments load straight from global in MFMA layout; residual
// re-reads the same (L1/L2-hot) tile in C-layout with immediate offsets.
__global__ __launch_bounds__(256)
void stgcn_wavefree(const float* __restrict__ x,
                    const float* __restrict__ w1, const float* __restrict__ b1,
                    const float* __restrict__ w2, const float* __restrict__ b2,
                    const float* __restrict__ gamma, const float* __restrict__ beta,
                    float* __restrict__ out)
{
    const int tid = threadIdx.x;
    const int l   = tid & 63;
    const int wv  = tid >> 6;
    const int lr  = l & 15;        // A-row / C-col within 16
    const int lc  = l >> 4;        // 0..3

    const int w  = blockIdx.x * 4 + wv;    // global wave id, 0..6047
    const int tc = w % NCH;
    const int nt = (w / NCH) % NT;
    const int b  = w / (NCH * NT);
    const int t0 = tc * TCH;
    const int n0 = nt * 16;

    // ---- persistent B-fragments: B[k][d] = 0.5*w[d][k], d = lr+16nf, k = lc*8+j+32ks
    bf16x8 B1[4][2], B2[4][2];
#pragma unroll
    for (int nf = 0; nf < 4; ++nf) {
#pragma unroll
        for (int ks = 0; ks < 2; ++ks) {
            const float* p1 = &w1[(size_t)(lr + 16*nf) * DD + lc*8 + 32*ks];
            const float* p2 = &w2[(size_t)(lr + 16*nf) * DD + lc*8 + 32*ks];
            f32x4 u0 = *(const f32x4*)p1, u1 = *(const f32x4*)(p1 + 4);
            f32x4 v0 = *(const f32x4*)p2, v1 = *(const f32x4*)(p2 + 4);
#pragma unroll
            for (int j = 0; j < 4; ++j) {
                B1[nf][ks][j]     = f2bf(0.5f * u0[j]);
                B1[nf][ks][4 + j] = f2bf(0.5f * u1[j]);
                B2[nf][ks][j]     = f2bf(0.5f * v0[j]);
                B2[nf][ks][4 + j] = f2bf(0.5f * v1[j]);
            }
        }
    }
    float bia1[4], bia2[4], gam[4], bet[4];
#pragma unroll
    for (int nf = 0; nf < 4; ++nf) {
        bia1[nf] = b1[lr + 16*nf];
        bia2[nf] = b2[lr + 16*nf];
        gam[nf]  = gamma[lr + 16*nf];
        bet[nf]  = beta[lr + 16*nf];
    }

    // ---- element offsets within one [NN][DD] timestep slab
    const int rowA = min(n0 + lr, NN - 1);            // clamped A-row
    const int offA = rowA * DD + lc * 8;              // + imm {0,4,32,36}
    int offX[4];                                      // C-layout row base
#pragma unroll
    for (int i = 0; i < 4; ++i)
        offX[i] = min(n0 + lc*4 + i, NN - 1) * DD + lr;   // + imm 16*nf

    // ---- x_prev in A-layout, bf16-packed (4 regs)
    bf16x8 xpb[2];
    if (t0 > 0) {
        const float* pg = x + (size_t)(b*TT + t0 - 1) * NN * DD;
        f32x4 q0 = *(const f32x4*)(pg + offA);
        f32x4 q1 = *(const f32x4*)(pg + offA + 4);
        f32x4 q2 = *(const f32x4*)(pg + offA + 32);
        f32x4 q3 = *(const f32x4*)(pg + offA + 36);
#pragma unroll
        for (int j = 0; j < 4; ++j) {
            xpb[0][j]     = f2bf(q0[j]);
            xpb[0][4 + j] = f2bf(q1[j]);
            xpb[1][j]     = f2bf(q2[j]);
            xpb[1][4 + j] = f2bf(q3[j]);
        }
    } else {
#pragma unroll
        for (int j = 0; j < 8; ++j) { xpb[0][j] = 0; xpb[1][j] = 0; }
    }

    const size_t ts = (size_t)NN * DD;
    const float* px = x   + (size_t)(b*TT + t0) * ts;
    float*       po = out + (size_t)(b*TT + t0) * ts;

#pragma unroll 1
    for (int t = 0; t < TCH; ++t) {
        // A-source tile, straight from global in MFMA A-layout
        f32x4 q0 = *(const f32x4*)(px + offA);
        f32x4 q1 = *(const f32x4*)(px + offA + 4);
        f32x4 q2 = *(const f32x4*)(px + offA + 32);
        f32x4 q3 = *(const f32x4*)(px + offA + 36);

        // residual in C-layout (same tile, L1/L2-hot; imm offsets 16*nf)
        float xr[4][4];
#pragma unroll
        for (int i = 0; i < 4; ++i)
#pragma unroll
            for (int nf = 0; nf < 4; ++nf)
                xr[i][nf] = px[offX[i] + 16*nf];

        // a = x_t + x_{t-1} (0.5 folded into weights), bf16
        bf16x8 A[2];
#pragma unroll
        for (int j = 0; j < 4; ++j) {
            A[0][j]     = f2bf(q0[j] + bf2f(xpb[0][j]));
            A[0][4 + j] = f2bf(q1[j] + bf2f(xpb[0][4 + j]));
            A[1][j]     = f2bf(q2[j] + bf2f(xpb[1][j]));
            A[1][4 + j] = f2bf(q3[j] + bf2f(xpb[1][4 + j]));
        }
#pragma unroll
        for (int j = 0; j < 4; ++j) {
            xpb[0][j]     = f2bf(q0[j]);
            xpb[0][4 + j] = f2bf(q1[j]);
            xpb[1][j]     = f2bf(q2[j]);
            xpb[1][4 + j] = f2bf(q3[j]);
        }

        // h = a @ (0.5*w^T), K=64
        f32x4 C1[4], C2[4];
#pragma unroll
        for (int nf = 0; nf < 4; ++nf) { C1[nf] = 0; C2[nf] = 0; }
#pragma unroll
        for (int nf = 0; nf < 4; ++nf) {
#pragma unroll
            for (int ks = 0; ks < 2; ++ks) {
                C1[nf] = __builtin_amdgcn_mfma_f32_16x16x32_bf16(A[ks], B1[nf][ks], C1[nf], 0, 0, 0);
                C2[nf] = __builtin_amdgcn_mfma_f32_16x16x32_bf16(A[ks], B2[nf][ks], C2[nf], 0, 0, 0);
            }
        }

        // epilogue: bias, gate, residual, LayerNorm, store
        float o[4][4], s[4], s2[4];
#pragma unroll
        for (int i = 0; i < 4; ++i) { s[i] = 0.f; s2[i] = 0.f; }
#pragma unroll
        for (int i = 0; i < 4; ++i) {
#pragma unroll
            for (int nf = 0; nf < 4; ++nf) {
                float h1 = C1[nf][i] + bia1[nf];
                float h2 = C2[nf][i] + bia2[nf];
                float p  = h1 * h2;
                float oo = (p > 0.f ? p : 0.f) + h1 + xr[i][nf];
                o[i][nf] = oo;
                s[i]  += oo;
                s2[i] += oo * oo;
            }
        }
#pragma unroll
        for (int off = 8; off >= 1; off >>= 1) {
#pragma unroll
            for (int i = 0; i < 4; ++i) {
                s[i]  += __shfl_xor(s[i],  off, 64);
                s2[i] += __shfl_xor(s2[i], off, 64);
            }
        }
#pragma unroll
        for (int i = 0; i < 4; ++i) {
            float mu = s[i] * (1.f/64.f);
            float va = s2[i] * (1.f/64.f) - mu*mu;
            float rs = rsqrtf(va + 1e-5f);
            if (n0 + lc*4 + i < NN) {      // skip duplicate clamped rows
#pragma unroll
                for (int nf = 0; nf < 4; ++nf)
                    po[offX[i] + 16*nf] = (o[i][nf] - mu) * rs * gam[nf] + bet[nf];
            }
        }

        px += ts; po += ts;
    }
}

extern "C" void kernel_launch(void* const* d_in, const int* in_sizes, int n_in,
                              void* d_out, int out_size, void* d_ws, size_t ws_size,
                              hipStream_t stream) {
    const float* x     = (const float*)d_in[0];
    // d_in[1] = adj — dead in the reference (overwritten by tiled identity)
    const float* w1    = (const float*)d_in[2];
    const float* b1    = (const float*)d_in[3];
    const float* w2    = (const float*)d_in[4];
    const float* b2    = (const float*)d_in[5];
    const float* gamma = (const float*)d_in[6];
    const float* beta  = (const float*)d_in[7];
    float* out = (float*)d_out;

    dim3 grid(32 * NT * NCH / 4);   // 6048 waves / 4 per block = 1512 blocks
    dim3 block(256);
    hipLaunchKernelGGL(stgcn_wavefree, grid, block, 0, stream,
                       x, w1, b1, w2, b2, gamma, beta, out);
}

// Round 6
// 110.303 us; speedup vs baseline: 1.0970x; 1.0970x over previous
//
#include <hip/hip_runtime.h>
#include <hip/hip_bf16.h>

#define TT 24
#define NN 1000
#define DD 64
#define TCH 8                  // timesteps per wave
#define NCH (TT / TCH)         // 3 chunks
#define NT  63                 // ceil(1000/16) node tiles

typedef short bf16x8 __attribute__((ext_vector_type(8)));
typedef float f32x4  __attribute__((ext_vector_type(4)));

__device__ __forceinline__ short f2bf(float f) {
    __hip_bfloat16 h = __float2bfloat16(f);
    return *reinterpret_cast<short*>(&h);
}

// Depth-1 software-pipelined, barrier-free. One wave = 16 nodes x 8 timesteps.
// h_t = 0.5w@x_t + 0.5w@x_{t-1} as two MFMA passes (decouples the t-chain);
// next tile prefetched into regs while current step computes; all global
// addresses are SGPR slab base + loop-invariant per-lane offset + immediate.
__global__ __launch_bounds__(256)
void stgcn_pf(const float* __restrict__ x,
              const float* __restrict__ w1, const float* __restrict__ b1,
              const float* __restrict__ w2, const float* __restrict__ b2,
              const float* __restrict__ gamma, const float* __restrict__ beta,
              float* __restrict__ out)
{
    const int tid = threadIdx.x;
    const int l   = tid & 63;
    const int wv  = tid >> 6;
    const int lr  = l & 15;        // A-row / C-col within 16
    const int lc  = l >> 4;        // 0..3

    // wave-uniform item id -> SGPR so slab bases become scalar
    const int w  = __builtin_amdgcn_readfirstlane(blockIdx.x * 4 + wv);
    const int nt = w % NT;                 // fastest: neighbor waves share slab
    const int tc = (w / NT) % NCH;
    const int b  = w / (NT * NCH);
    const int t0 = tc * TCH;
    const int n0 = nt * 16;

    // ---- persistent B-fragments: B[k][d] = 0.5*w[d][k]
    bf16x8 B1[4][2], B2[4][2];
#pragma unroll
    for (int nf = 0; nf < 4; ++nf) {
#pragma unroll
        for (int ks = 0; ks < 2; ++ks) {
            const float* p1 = &w1[(size_t)(lr + 16*nf) * DD + lc*8 + 32*ks];
            const float* p2 = &w2[(size_t)(lr + 16*nf) * DD + lc*8 + 32*ks];
            f32x4 u0 = *(const f32x4*)p1, u1 = *(const f32x4*)(p1 + 4);
            f32x4 v0 = *(const f32x4*)p2, v1 = *(const f32x4*)(p2 + 4);
#pragma unroll
            for (int j = 0; j < 4; ++j) {
                B1[nf][ks][j]     = f2bf(0.5f * u0[j]);
                B1[nf][ks][4 + j] = f2bf(0.5f * u1[j]);
                B2[nf][ks][j]     = f2bf(0.5f * v0[j]);
                B2[nf][ks][4 + j] = f2bf(0.5f * v1[j]);
            }
        }
    }
    float bia1[4], bia2[4], gam[4], bet[4];
#pragma unroll
    for (int nf = 0; nf < 4; ++nf) {
        bia1[nf] = b1[lr + 16*nf];
        bia2[nf] = b2[lr + 16*nf];
        gam[nf]  = gamma[lr + 16*nf];
        bet[nf]  = beta[lr + 16*nf];
    }

    // ---- loop-invariant per-lane word offsets within a [NN][DD] slab
    const int rowA = min(n0 + lr, NN - 1);
    const int offA = rowA * DD + lc * 8;           // + imm {0,4,32,36} words
    int offX[4];
#pragma unroll
    for (int i = 0; i < 4; ++i)
        offX[i] = min(n0 + lc*4 + i, NN - 1) * DD + lr;   // + imm 16*nf words

    const size_t ts = (size_t)NN * DD;
    const float* px = x   + (size_t)(b*TT + t0) * ts;     // SGPR slab base
    float*       po = out + (size_t)(b*TT + t0) * ts;

    // ---- x_{t0-1} -> Am (bf16 A-frags); zero-pad at t0==0
    bf16x8 AmA[2], AmB[2];
    if (t0 > 0) {
        const float* pm = px - ts;
        f32x4 m0 = *(const f32x4*)(pm + offA);
        f32x4 m1 = *(const f32x4*)(pm + offA + 4);
        f32x4 m2 = *(const f32x4*)(pm + offA + 32);
        f32x4 m3 = *(const f32x4*)(pm + offA + 36);
#pragma unroll
        for (int j = 0; j < 4; ++j) {
            AmA[0][j]     = f2bf(m0[j]);
            AmA[0][4 + j] = f2bf(m1[j]);
            AmA[1][j]     = f2bf(m2[j]);
            AmA[1][4 + j] = f2bf(m3[j]);
        }
    } else {
        AmA[0] = 0; AmA[1] = 0;
    }

    // ---- prologue: stage A <- x_t0
    f32x4 qA0 = *(const f32x4*)(px + offA);
    f32x4 qA1 = *(const f32x4*)(px + offA + 4);
    f32x4 qA2 = *(const f32x4*)(px + offA + 32);
    f32x4 qA3 = *(const f32x4*)(px + offA + 36);
    f32x4 qB0, qB1, qB2, qB3;

    const f32x4 fzero = 0;

    auto step = [&](int t,
                    f32x4& q0, f32x4& q1, f32x4& q2, f32x4& q3,   // current (arrived)
                    f32x4& p0, f32x4& p1, f32x4& p2, f32x4& p3,   // prefetch dest
                    bf16x8 (&Ami)[2], bf16x8 (&Amo)[2]) {
        // residual loads for this t (tile is L1/L2-hot from its own prefetch)
        const float* pc = px + (size_t)t * ts;
        float xr[4][4];
#pragma unroll
        for (int i = 0; i < 4; ++i)
#pragma unroll
            for (int nf = 0; nf < 4; ++nf)
                xr[i][nf] = pc[offX[i] + 16*nf];

        // prefetch next tile (clamped at chunk end; in-bounds, unused)
        const float* pn = px + (size_t)min(t + 1, TCH - 1) * ts;
        p0 = *(const f32x4*)(pn + offA);
        p1 = *(const f32x4*)(pn + offA + 4);
        p2 = *(const f32x4*)(pn + offA + 32);
        p3 = *(const f32x4*)(pn + offA + 36);

        // x_{t-1}-side MFMAs first: inputs already in regs, no waits
        f32x4 C1[4], C2[4];
#pragma unroll
        for (int nf = 0; nf < 4; ++nf) {
            C1[nf] = __builtin_amdgcn_mfma_f32_16x16x32_bf16(Ami[0], B1[nf][0], fzero,  0, 0, 0);
            C1[nf] = __builtin_amdgcn_mfma_f32_16x16x32_bf16(Ami[1], B1[nf][1], C1[nf], 0, 0, 0);
            C2[nf] = __builtin_amdgcn_mfma_f32_16x16x32_bf16(Ami[0], B2[nf][0], fzero,  0, 0, 0);
            C2[nf] = __builtin_amdgcn_mfma_f32_16x16x32_bf16(Ami[1], B2[nf][1], C2[nf], 0, 0, 0);
        }

        // convert current tile straight into next step's Am (no copy)
#pragma unroll
        for (int j = 0; j < 4; ++j) {
            Amo[0][j]     = f2bf(q0[j]);
            Amo[0][4 + j] = f2bf(q1[j]);
            Amo[1][j]     = f2bf(q2[j]);
            Amo[1][4 + j] = f2bf(q3[j]);
        }
#pragma unroll
        for (int nf = 0; nf < 4; ++nf) {
            C1[nf] = __builtin_amdgcn_mfma_f32_16x16x32_bf16(Amo[0], B1[nf][0], C1[nf], 0, 0, 0);
            C1[nf] = __builtin_amdgcn_mfma_f32_16x16x32_bf16(Amo[1], B1[nf][1], C1[nf], 0, 0, 0);
            C2[nf] = __builtin_amdgcn_mfma_f32_16x16x32_bf16(Amo[0], B2[nf][0], C2[nf], 0, 0, 0);
            C2[nf] = __builtin_amdgcn_mfma_f32_16x16x32_bf16(Amo[1], B2[nf][1], C2[nf], 0, 0, 0);
        }

        // epilogue: bias, gate, residual, LayerNorm, store (C1 reused as o)
        float s[4] = {0,0,0,0}, s2[4] = {0,0,0,0};
#pragma unroll
        for (int i = 0; i < 4; ++i)
#pragma unroll
            for (int nf = 0; nf < 4; ++nf) {
                float h1 = C1[nf][i] + bia1[nf];
                float h2 = C2[nf][i] + bia2[nf];
                float pg = h1 * h2;
                float oo = (pg > 0.f ? pg : 0.f) + h1 + xr[i][nf];
                C1[nf][i] = oo;
                s[i]  += oo;
                s2[i] += oo * oo;
            }
#pragma unroll
        for (int off = 8; off >= 1; off >>= 1)
#pragma unroll
            for (int i = 0; i < 4; ++i) {
                s[i]  += __shfl_xor(s[i],  off, 64);
                s2[i] += __shfl_xor(s2[i], off, 64);
            }
        float* pot = po + (size_t)t * ts;
#pragma unroll
        for (int i = 0; i < 4; ++i) {
            float mu = s[i] * (1.f/64.f);
            float va = s2[i] * (1.f/64.f) - mu*mu;
            float rs = rsqrtf(va + 1e-5f);
            if (n0 + lc*4 + i < NN) {
#pragma unroll
                for (int nf = 0; nf < 4; ++nf)
                    pot[offX[i] + 16*nf] = (C1[nf][i] - mu) * rs * gam[nf] + bet[nf];
            }
        }
    };

#pragma unroll 1
    for (int t = 0; t < TCH; t += 2) {
        step(t,     qA0,qA1,qA2,qA3,  qB0,qB1,qB2,qB3,  AmA, AmB);
        step(t + 1, qB0,qB1,qB2,qB3,  qA0,qA1,qA2,qA3,  AmB, AmA);
    }
}

extern "C" void kernel_launch(void* const* d_in, const int* in_sizes, int n_in,
                              void* d_out, int out_size, void* d_ws, size_t ws_size,
                              hipStream_t stream) {
    const float* x     = (const float*)d_in[0];
    // d_in[1] = adj — dead in the reference (overwritten by tiled identity)
    const float* w1    = (const float*)d_in[2];
    const float* b1    = (const float*)d_in[3];
    const float* w2    = (const float*)d_in[4];
    const float* b2    = (const float*)d_in[5];
    const float* gamma = (const float*)d_in[6];
    const float* beta  = (const float*)d_in[7];
    float* out = (float*)d_out;

    dim3 grid(32 * NT * NCH / 4);   // 6048 waves / 4 per block = 1512 blocks
    dim3 block(256);
    hipLaunchKernelGGL(stgcn_pf, grid, block, 0, stream,
                       x, w1, b1, w2, b2, gamma, beta, out);
}